// Round 4
// baseline (11215.942 us; speedup 1.0000x reference)
//
#include <hip/hip_runtime.h>
#include <hip/hip_bf16.h>
#include <math.h>

// ---------------------------------------------------------------------------
// SecretRQVAE. d_out is FLOAT32 (reference outputs are jnp.float32; round-2's
// 1025.0 recon error == bf16 index values read through f32 words at halved
// offsets proved it). Inputs may be bf16 or f32 -> runtime bit-pattern sniff.
//
// Outputs (f32, concatenated): recon[3145728] | indices[262144] | loss[4] |
//                              q_chw[16777216]
// Workspace (exactly 128 MB):
//   PA [0,64MB):  h1 f32 -> h3 f32 -> D1 f32 (lower 32MB)
//                 (+48MB: cnh 16KB, idxB 1MB, flg 256KB, lossP 256KB - only
//                  live after conv4, through the VQ phase)
//   PB [64,128MB): h2 f32 (lower 32MB) -> z/residual f32 [d][n] -> D2 f32
// Round 3 failed on infra ("container failed twice") -- source unchanged.
// ---------------------------------------------------------------------------

#define DEVFN static __device__ __forceinline__
DEVFN float b2f(__hip_bfloat16 v){ return __bfloat162float(v); }
DEVFN float ldv(const float* p, long long i){ return p[i]; }
DEVFN float ldv(const __hip_bfloat16* p, long long i){ return b2f(p[i]); }

// true if array at p is f32 (vs packed bf16). Uses bits 7..14 of 64 u32 words:
// for bf16 pairs that's the low element's exponent (Gaussian data -> [118,134]);
// for f32 those are mantissa bits (uniform).
DEVFN bool sniff_f32(const void* p){
  const unsigned* u = (const unsigned*)p;
  int hits = 0;
  #pragma unroll
  for (int i=0;i<64;i++){
    unsigned b = (u[i]>>7)&0xFFu;
    hits += (b>=118u && b<=134u) ? 1 : 0;
  }
  return hits < 32;
}

// ============================ conv1: 3->64, 4x4 s2 p1, relu ==================
template<class T>
DEVFN void conv1_impl(const T* __restrict__ x, const T* __restrict__ w,
                      const T* __restrict__ bias, float* __restrict__ out,
                      float* ws, float* bs)
{
  for (int i = threadIdx.x; i < 3072; i += 256) ws[i] = ldv(w, i);
  if (threadIdx.x < 64) bs[threadIdx.x] = ldv(bias, threadIdx.x);
  __syncthreads();
  int gid = blockIdx.x*256 + threadIdx.x;            // ((b*64+co)*128+oy)*128+ox
  int ox = gid & 127, oy = (gid>>7)&127, co = (gid>>14)&63, b = gid>>20;
  float acc = bs[co];
  const T* xb = x + (long long)b*196608;
  for (int ci=0; ci<3; ci++){
    #pragma unroll
    for (int ky=0; ky<4; ky++){
      int iy = 2*oy + ky - 1;
      if ((unsigned)iy >= 256u) continue;
      #pragma unroll
      for (int kx=0; kx<4; kx++){
        int ix = 2*ox + kx - 1;
        if ((unsigned)ix >= 256u) continue;
        acc += ldv(xb, (ci*256+iy)*256+ix) * ws[(co*3+ci)*16 + ky*4+kx];
      }
    }
  }
  out[gid] = fmaxf(acc, 0.f);
}

__global__ __launch_bounds__(256) void k_conv1(const void* x, const void* w,
    const void* bias, float* out)
{
  __shared__ float ws[3072]; __shared__ float bs[64];
  if (sniff_f32(w)) conv1_impl((const float*)x, (const float*)w, (const float*)bias, out, ws, bs);
  else conv1_impl((const __hip_bfloat16*)x, (const __hip_bfloat16*)w, (const __hip_bfloat16*)bias, out, ws, bs);
}

// ============================ conv2: 64->128, 4x4 s2 p1, relu ================
template<class TW>
DEVFN void conv2_impl(const float* __restrict__ in, const TW* __restrict__ w,
                      const TW* __restrict__ bias, float* __restrict__ out,
                      float* lin, float* lw, float* lb)
{
  const int tid = threadIdx.x;
  const int tx = blockIdx.x & 3, ty = blockIdx.x >> 2;  // 4 x-tiles, 8 y-tiles
  const int b = blockIdx.y, cg = blockIdx.z;
  if (tid < 64) lb[tid] = ldv(bias, cg*64+tid);
  __syncthreads();
  const int pxg = tid & 31, cog = tid >> 5;
  const int y = pxg >> 2, xb = (pxg & 3) << 2;
  float acc[4][8];
  #pragma unroll
  for (int i=0;i<4;i++)
    #pragma unroll
    for (int j=0;j<8;j++) acc[i][j] = lb[cog*8+j];
  const int oy0 = ty*8, ox0 = tx*16;
  const int iy0 = 2*oy0 - 1, ix0 = 2*ox0 - 1;
  for (int cc0 = 0; cc0 < 64; cc0 += 4){
    for (int j = tid; j < 4*18*34; j += 256){
      int cc = j / 612, rem = j % 612, r = rem / 34, cx = rem % 34;
      int iy = iy0 + r, ix = ix0 + cx;
      float v = 0.f;
      if ((unsigned)iy < 128u && (unsigned)ix < 128u)
        v = in[((b*64 + cc0+cc)*128 + iy)*128 + ix];
      lin[(cc*18 + r)*35 + cx] = v;
    }
    for (int j = tid; j < 4096; j += 256){
      int tap = j & 15, cc = (j>>4) & 3, co = j >> 6;
      lw[(cc*16+tap)*68 + co] = ldv(w, ((cg*64+co)*64 + cc0+cc)*16 + tap);
    }
    __syncthreads();
    #pragma unroll
    for (int cc=0; cc<4; cc++){
      #pragma unroll
      for (int ky=0; ky<4; ky++){
        #pragma unroll
        for (int kx=0; kx<4; kx++){
          float a0 = lin[(cc*18 + 2*y+ky)*35 + 2*(xb+0)+kx];
          float a1 = lin[(cc*18 + 2*y+ky)*35 + 2*(xb+1)+kx];
          float a2 = lin[(cc*18 + 2*y+ky)*35 + 2*(xb+2)+kx];
          float a3 = lin[(cc*18 + 2*y+ky)*35 + 2*(xb+3)+kx];
          const float* wp = &lw[(cc*16 + ky*4+kx)*68 + cog*8];
          #pragma unroll
          for (int j=0;j<8;j++){
            float wv = wp[j];
            acc[0][j] += a0*wv; acc[1][j] += a1*wv;
            acc[2][j] += a2*wv; acc[3][j] += a3*wv;
          }
        }
      }
    }
    __syncthreads();
  }
  #pragma unroll
  for (int j=0;j<8;j++){
    int co = cg*64 + cog*8 + j;
    #pragma unroll
    for (int i=0;i<4;i++)
      out[((b*128 + co)*64 + oy0+y)*64 + ox0+xb+i] = fmaxf(acc[i][j], 0.f);
  }
}

__global__ __launch_bounds__(256) void k_conv2(const float* in, const void* w,
    const void* bias, float* out)
{
  __shared__ __align__(16) float lin[4*18*35];
  __shared__ __align__(16) float lw[4*16*68];
  __shared__ float lb[64];
  if (sniff_f32(w)) conv2_impl(in, (const float*)w, (const float*)bias, out, lin, lw, lb);
  else conv2_impl(in, (const __hip_bfloat16*)w, (const __hip_bfloat16*)bias, out, lin, lw, lb);
}

// ============================ 3x3 s1 p1 conv (conv3/conv4/dec1) =============
// IN_Q: input is q_chw in d_out, layout [b][c][hw]. OUT_T: write z as [d][n].
template<int CI, bool RELU, bool IN_Q, bool OUT_T, class TW>
DEVFN void conv3_impl(const float* __restrict__ in, const TW* __restrict__ w,
                      const TW* __restrict__ bias, float* __restrict__ out,
                      float* lin, float* lw, float* lb)
{
  const int tid = threadIdx.x;
  const int tx = blockIdx.x & 3, ty = blockIdx.x >> 2;
  const int b = blockIdx.y, cg = blockIdx.z;
  const int CO = gridDim.z * 64;
  if (tid < 64) lb[tid] = ldv(bias, cg*64+tid);
  __syncthreads();
  const int pxg = tid & 31, cog = tid >> 5;
  const int y = pxg >> 2, xb = (pxg & 3) << 2;
  float acc[4][8];
  #pragma unroll
  for (int i=0;i<4;i++)
    #pragma unroll
    for (int j=0;j<8;j++) acc[i][j] = lb[cog*8+j];
  const int oy0 = ty*8, ox0 = tx*16;
  for (int cc0 = 0; cc0 < CI; cc0 += 8){
    for (int j = tid; j < 1440; j += 256){
      int cc = j / 180, r = (j % 180) / 18, cx = j % 18;
      int iy = oy0 - 1 + r, ix = ox0 - 1 + cx;
      float v = 0.f;
      if ((unsigned)iy < 64u && (unsigned)ix < 64u)
        v = IN_Q ? in[b*1048576 + (cc0+cc)*4096 + iy*64 + ix]
                 : in[((b*CI + cc0+cc)*64 + iy)*64 + ix];
      lin[(cc*10 + r)*19 + cx] = v;
    }
    for (int j = tid; j < 4608; j += 256){
      int tap = j % 9, cc = (j/9) & 7, co = j / 72;
      lw[(cc*9+tap)*68 + co] = ldv(w, ((cg*64+co)*CI + cc0+cc)*9 + tap);
    }
    __syncthreads();
    #pragma unroll
    for (int cc=0; cc<8; cc++){
      #pragma unroll
      for (int dy=0; dy<3; dy++){
        #pragma unroll
        for (int dx=0; dx<3; dx++){
          float a0 = lin[(cc*10 + y+dy)*19 + xb+dx+0];
          float a1 = lin[(cc*10 + y+dy)*19 + xb+dx+1];
          float a2 = lin[(cc*10 + y+dy)*19 + xb+dx+2];
          float a3 = lin[(cc*10 + y+dy)*19 + xb+dx+3];
          const float* wp = &lw[(cc*9 + dy*3+dx)*68 + cog*8];
          #pragma unroll
          for (int j=0;j<8;j++){
            float wv = wp[j];
            acc[0][j] += a0*wv; acc[1][j] += a1*wv;
            acc[2][j] += a2*wv; acc[3][j] += a3*wv;
          }
        }
      }
    }
    __syncthreads();
  }
  #pragma unroll
  for (int j=0;j<8;j++){
    int co = cg*64 + cog*8 + j;
    #pragma unroll
    for (int i=0;i<4;i++){
      int oy = oy0 + y, ox = ox0 + xb + i;
      float v = acc[i][j];
      if (RELU) v = fmaxf(v, 0.f);
      if (OUT_T) out[co*65536 + b*4096 + oy*64 + ox] = v;
      else       out[((b*CO + co)*64 + oy)*64 + ox] = v;
    }
  }
}

template<int CI, bool RELU, bool IN_Q, bool OUT_T>
__global__ __launch_bounds__(256) void k_conv3x3(const float* in, const void* w,
    const void* bias, float* out)
{
  __shared__ __align__(16) float lin[8*10*19];
  __shared__ __align__(16) float lw[8*9*68];
  __shared__ float lb[64];
  if (sniff_f32(w)) conv3_impl<CI,RELU,IN_Q,OUT_T>(in, (const float*)w, (const float*)bias, out, lin, lw, lb);
  else conv3_impl<CI,RELU,IN_Q,OUT_T>(in, (const __hip_bfloat16*)w, (const __hip_bfloat16*)bias, out, lin, lw, lb);
}

// ============================ codebook 0.5*||c||^2 ===========================
template<class T>
DEVFN void cnh_impl(const T* __restrict__ cb, float* __restrict__ cnh, float* ps)
{
  int row = blockIdx.x;                  // q*1024 + k
  float v = ldv(cb, (long long)row*256 + threadIdx.x);
  float s = v*v;
  for (int o=32;o>0;o>>=1) s += __shfl_down(s, o, 64);
  if ((threadIdx.x & 63) == 0) ps[threadIdx.x>>6] = s;
  __syncthreads();
  if (threadIdx.x == 0) cnh[row] = 0.5f*(ps[0]+ps[1]+ps[2]+ps[3]);
}

__global__ __launch_bounds__(256) void k_cnh(const void* cb, float* cnh)
{
  __shared__ float ps[4];
  if (sniff_f32(cb)) cnh_impl((const float*)cb, cnh, ps);
  else cnh_impl((const __hip_bfloat16*)cb, cnh, ps);
}

// ============================ VQ argmin (f32) with near-tie flag =============
// koff: element offset of this quantizer's codebook within cb (q*262144).
template<class TCB>
DEVFN void argmin_impl(const float* __restrict__ resT, const TCB* __restrict__ cb,
    long long koff, const float* __restrict__ cnh,
    int* __restrict__ idxOut, int* __restrict__ flagOut,
    float* lp, float* lc, float* rm1, float* rm2, int* ri1)
{
  const int tid = threadIdx.x;
  const int n0 = blockIdx.x * 64;
  const int tp = tid & 15, tc = tid >> 4;
  float m1[4], m2[4]; int i1[4];
  #pragma unroll
  for (int i=0;i<4;i++){ m1[i]=INFINITY; m2[i]=INFINITY; i1[i]=0; }
  for (int ct=0; ct<8; ct++){
    const int k0 = ct*128;
    float acc[4][8];
    #pragma unroll
    for (int i=0;i<4;i++)
      #pragma unroll
      for (int j=0;j<8;j++) acc[i][j]=0.f;
    for (int dc=0; dc<8; dc++){
      const int d0 = dc*32;
      for (int j=tid; j<2048; j+=256){ int dd=j>>6, p=j&63; lp[dd*64+p] = resT[(d0+dd)*65536 + n0+p]; }
      for (int j=tid; j<4096; j+=256){ int dd=j&31, kk=j>>5; lc[dd*132+kk] = ldv(cb, koff + (long long)(k0+kk)*256 + d0+dd); }
      __syncthreads();
      #pragma unroll 4
      for (int dd=0; dd<32; dd++){
        float a[4]; float c[8];
        *(float4*)&a[0] = *(const float4*)&lp[dd*64 + 4*tp];
        *(float4*)&c[0] = *(const float4*)&lc[dd*132 + 8*tc];
        *(float4*)&c[4] = *(const float4*)&lc[dd*132 + 8*tc + 4];
        #pragma unroll
        for (int i=0;i<4;i++)
          #pragma unroll
          for (int j=0;j<8;j++) acc[i][j] += a[i]*c[j];
      }
      __syncthreads();
    }
    #pragma unroll
    for (int j=0;j<8;j++){
      int k = k0 + 8*tc + j;
      float cn = cnh[k];
      #pragma unroll
      for (int i=0;i<4;i++){
        float s = cn - acc[i][j];
        if (s < m1[i]) { m2[i] = m1[i]; m1[i] = s; i1[i] = k; }
        else if (s < m2[i]) m2[i] = s;
      }
    }
  }
  #pragma unroll
  for (int i=0;i<4;i++){
    rm1[(4*tp+i)*17 + tc] = m1[i];
    rm2[(4*tp+i)*17 + tc] = m2[i];
    ri1[(4*tp+i)*17 + tc] = i1[i];
  }
  __syncthreads();
  if (tid < 64){
    float bm1 = INFINITY, bm2 = INFINITY; int bi = 0;
    for (int t=0;t<16;t++){
      float a = rm1[tid*17+t], b2v = rm2[tid*17+t]; int ia = ri1[tid*17+t];
      if (a < bm1 || (a == bm1 && ia < bi)){ bm2 = fminf(bm1, b2v); bm1 = a; bi = ia; }
      else bm2 = fminf(bm2, fminf(a, b2v));
    }
    idxOut[n0 + tid] = bi;
    float tau = 1e-3f * (fabsf(bm1) + 1.0f);
    flagOut[n0 + tid] = (bm2 - bm1 < tau) ? 1 : 0;
  }
}

__global__ __launch_bounds__(256) void k_argmin(const float* resT, const void* cb,
    long long koff, const float* cnh, int* idxOut, int* flagOut)
{
  __shared__ __align__(16) float lp[32*64];
  __shared__ __align__(16) float lc[32*132];
  __shared__ float rm1[64*17], rm2[64*17];
  __shared__ int   ri1[64*17];
  if (sniff_f32(cb)) argmin_impl(resT, (const float*)cb, koff, cnh, idxOut, flagOut, lp, lc, rm1, rm2, ri1);
  else argmin_impl(resT, (const __hip_bfloat16*)cb, koff, cnh, idxOut, flagOut, lp, lc, rm1, rm2, ri1);
}

// ============================ f64 fixup for near-tie points ==================
template<class TCB>
DEVFN void fixup_impl(const float* __restrict__ resT, const TCB* __restrict__ cb,
    long long koff, const int* __restrict__ flags, int* __restrict__ idxOut,
    double* bm, int* bis, float* rsh)
{
  const int tid = threadIdx.x;
  const int n0 = blockIdx.x * 64;
  for (int p=0; p<64; p++){
    int n = n0 + p;
    if (!flags[n]) continue;                 // uniform per block
    rsh[tid] = resT[tid*65536 + n];
    __syncthreads();
    double best = INFINITY; int bidx = 0;
    for (int c=0; c<4; c++){
      int k = tid*4 + c;
      double s = 0.0;
      for (int d=0; d<256; d++){
        double cv = (double)ldv(cb, koff + (long long)k*256 + d);
        s += cv*(cv - 2.0*(double)rsh[d]);   // ||c||^2 - 2 r.c
      }
      if (s < best || (s == best && k < bidx)){ best = s; bidx = k; }
    }
    bm[tid] = best; bis[tid] = bidx;
    __syncthreads();
    for (int st=128; st>0; st>>=1){
      if (tid < st){
        if (bm[tid+st] < bm[tid] || (bm[tid+st] == bm[tid] && bis[tid+st] < bis[tid])){
          bm[tid] = bm[tid+st]; bis[tid] = bis[tid+st];
        }
      }
      __syncthreads();
    }
    if (tid == 0) idxOut[n] = bis[0];
    __syncthreads();
  }
}

__global__ __launch_bounds__(256) void k_fixup(const float* resT, const void* cb,
    long long koff, const int* flags, int* idxOut)
{
  __shared__ double bm[256]; __shared__ int bis[256];
  __shared__ float rsh[256];
  if (sniff_f32(cb)) fixup_impl(resT, (const float*)cb, koff, flags, idxOut, bm, bis, rsh);
  else fixup_impl(resT, (const __hip_bfloat16*)cb, koff, flags, idxOut, bm, bis, rsh);
}

// ============================ VQ update: gather, loss, residual, q-accum =====
template<bool FIRST, class TCB>
DEVFN void update_impl(const TCB* __restrict__ cb, long long koff,
    const int* __restrict__ idx, float* __restrict__ resT,
    float* __restrict__ qf, float* __restrict__ lossP, float* ps)
{
  int gid = blockIdx.x*256 + threadIdx.x;    // [d][n], n fastest
  int n = gid & 65535, d = gid >> 16;
  int b = n >> 12, hw = n & 4095;
  float r = resT[gid];
  float qv = ldv(cb, koff + (long long)idx[n]*256 + d);
  float diff = qv - r;
  resT[gid] = -diff;
  long long qo = (long long)b*1048576 + d*4096 + hw;   // [b][d][hw]
  qf[qo] = FIRST ? qv : (qf[qo] + qv);
  float t = diff*diff;
  for (int o=32;o>0;o>>=1) t += __shfl_down(t, o, 64);
  if ((threadIdx.x & 63) == 0) ps[threadIdx.x>>6] = t;
  __syncthreads();
  if (threadIdx.x == 0) lossP[blockIdx.x] = ps[0]+ps[1]+ps[2]+ps[3];
}

template<bool FIRST>
__global__ __launch_bounds__(256) void k_update(const void* cb, long long koff,
    const int* idx, float* resT, float* qf, float* lossP)
{
  __shared__ float ps[4];
  if (sniff_f32(cb)) update_impl<FIRST>((const float*)cb, koff, idx, resT, qf, lossP, ps);
  else update_impl<FIRST>((const __hip_bfloat16*)cb, koff, idx, resT, qf, lossP, ps);
}

__global__ __launch_bounds__(256) void k_lossred(const float* __restrict__ lossP,
    float* __restrict__ outp)
{
  double s = 0.0;
  for (int j = threadIdx.x; j < 65536; j += 256) s += (double)lossP[j];
  for (int o=32;o>0;o>>=1) s += __shfl_down(s, o, 64);
  __shared__ double ps[4];
  if ((threadIdx.x & 63) == 0) ps[threadIdx.x>>6] = s;
  __syncthreads();
  if (threadIdx.x == 0) *outp = (float)((ps[0]+ps[1]+ps[2]+ps[3]) / 16777216.0);
}

// ============================ indices writer =================================
__global__ __launch_bounds__(256) void k_write_idx(const int* __restrict__ idxAll,
    float* __restrict__ out)
{
  int gid = blockIdx.x*256 + threadIdx.x;    // ((b*4+q)*4096 + hw)
  int hw = gid & 4095, q = (gid>>12)&3, b = gid>>14;
  out[3145728 + gid] = (float)idxAll[q*65536 + b*4096 + hw];
}

// ============================ deconv1: 128->64, 4x4 s2 p1, relu ==============
template<class TW>
DEVFN void deconv1_impl(const float* __restrict__ in, const TW* __restrict__ w,
                        const TW* __restrict__ bias, float* __restrict__ out,
                        float* lin, float* lw, float* lb)
{
  const int tid = threadIdx.x;
  const int tx = blockIdx.x & 7, ty = blockIdx.x >> 3;   // 8 x-tiles, 16 y-tiles
  const int b = blockIdx.y;
  if (tid < 64) lb[tid] = ldv(bias, tid);
  __syncthreads();
  const int pxg = tid & 31, cog = tid >> 5;
  const int y = pxg >> 2, xb = (pxg & 3) << 2;
  float acc[4][8];
  #pragma unroll
  for (int i=0;i<4;i++)
    #pragma unroll
    for (int j=0;j<8;j++) acc[i][j] = lb[cog*8+j];
  const int oy0 = ty*8, ox0 = tx*16;
  const int iy0 = oy0 >> 1, ix0 = ox0 >> 1;
  const int kb = (y+1) & 1;
  const int e  = (y+1-kb) >> 1;
  for (int cc0 = 0; cc0 < 128; cc0 += 8){
    for (int j = tid; j < 480; j += 256){
      int cc = j / 60, r = (j % 60) / 10, cx = j % 10;
      int iy = iy0 - 1 + r, ix = ix0 - 1 + cx;
      float v = 0.f;
      if ((unsigned)iy < 64u && (unsigned)ix < 64u)
        v = in[((b*128 + cc0+cc)*64 + iy)*64 + ix];
      lin[(cc*6 + r)*11 + cx] = v;
    }
    for (int j = tid; j < 8192; j += 256){
      int tap = j & 15, co = (j>>4) & 63, cc = j >> 10;
      lw[(cc*16+tap)*68 + co] = ldv(w, ((cc0+cc)*64 + co)*16 + tap);
    }
    __syncthreads();
    #pragma unroll
    for (int cc=0; cc<8; cc++){
      #pragma unroll
      for (int kyi=0; kyi<2; kyi++){
        int ky = kb + 2*kyi;
        int riy = e - kyi + 1;
        #pragma unroll
        for (int kxi=0; kxi<2; kxi++){
          int rx = (xb>>1) - kxi;
          float a0 = lin[(cc*6 + riy)*11 + rx+1];
          float a1 = lin[(cc*6 + riy)*11 + rx+2];
          float a3 = lin[(cc*6 + riy)*11 + rx+3];
          const float* we = &lw[(cc*16 + ky*4 + 1 + 2*kxi)*68 + cog*8];
          const float* wo = &lw[(cc*16 + ky*4 + 0 + 2*kxi)*68 + cog*8];
          #pragma unroll
          for (int j=0;j<8;j++){
            acc[0][j] += a0*we[j];
            acc[1][j] += a1*wo[j];
            acc[2][j] += a1*we[j];
            acc[3][j] += a3*wo[j];
          }
        }
      }
    }
    __syncthreads();
  }
  #pragma unroll
  for (int j=0;j<8;j++){
    int co = cog*8 + j;
    #pragma unroll
    for (int i=0;i<4;i++)
      out[((b*64 + co)*128 + oy0+y)*128 + ox0+xb+i] = fmaxf(acc[i][j], 0.f);
  }
}

__global__ __launch_bounds__(256) void k_deconv1(const float* in, const void* w,
    const void* bias, float* out)
{
  __shared__ __align__(16) float lin[8*6*11];
  __shared__ __align__(16) float lw[8*16*68];
  __shared__ float lb[64];
  if (sniff_f32(w)) deconv1_impl(in, (const float*)w, (const float*)bias, out, lin, lw, lb);
  else deconv1_impl(in, (const __hip_bfloat16*)w, (const __hip_bfloat16*)bias, out, lin, lw, lb);
}

// ============================ deconv2: 64->3, 4x4 s2 p1, tanh ================
template<class TW>
DEVFN void deconv2_impl(const float* __restrict__ in, const TW* __restrict__ w,
                        const TW* __restrict__ bias, float* __restrict__ outp,
                        float* lw, float* lb)
{
  for (int j = threadIdx.x; j < 3072; j += 256) lw[j] = ldv(w, j);
  if (threadIdx.x < 3) lb[threadIdx.x] = ldv(bias, threadIdx.x);
  __syncthreads();
  int gid = blockIdx.x*256 + threadIdx.x;    // ((b*3+co)*256+oy)*256+ox
  int ox = gid & 255, oy = (gid>>8)&255;
  int c3 = gid >> 16; int co = c3 % 3; int b = c3 / 3;
  int kby = (oy+1)&1, kbx = (ox+1)&1;
  float acc = lb[co];
  const float* inb = in + (long long)b*64*16384;
  for (int ci=0; ci<64; ci++){
    const float* ic = inb + ci*16384;
    #pragma unroll
    for (int kyi=0; kyi<2; kyi++){
      int ky = kby + 2*kyi;
      int iy = oy + 1 - ky;
      if (iy < 0) continue;
      iy >>= 1;
      if (iy >= 128) continue;
      #pragma unroll
      for (int kxi=0; kxi<2; kxi++){
        int kx = kbx + 2*kxi;
        int ix = ox + 1 - kx;
        if (ix < 0) continue;
        ix >>= 1;
        if (ix >= 128) continue;
        acc += ic[iy*128+ix] * lw[(ci*3+co)*16 + ky*4+kx];
      }
    }
  }
  outp[gid] = tanhf(acc);
}

__global__ __launch_bounds__(256) void k_deconv2(const float* in, const void* w,
    const void* bias, float* outp)
{
  __shared__ float lw[3072]; __shared__ float lb[3];
  if (sniff_f32(w)) deconv2_impl(in, (const float*)w, (const float*)bias, outp, lw, lb);
  else deconv2_impl(in, (const __hip_bfloat16*)w, (const __hip_bfloat16*)bias, outp, lw, lb);
}

// ============================ launch =========================================
extern "C" void kernel_launch(void* const* d_in, const int* in_sizes, int n_in,
                              void* d_out, int out_size, void* d_ws, size_t ws_size,
                              hipStream_t stream)
{
  const void* x   = d_in[0];
  const void* w1  = d_in[1];  const void* b1  = d_in[2];
  const void* w2  = d_in[3];  const void* b2  = d_in[4];
  const void* w3  = d_in[5];  const void* b3  = d_in[6];
  const void* w4  = d_in[7];  const void* b4  = d_in[8];
  const void* cb  = d_in[9];
  const void* dw1 = d_in[10]; const void* db1 = d_in[11];
  const void* tw1 = d_in[12]; const void* tb1 = d_in[13];
  const void* tw2 = d_in[14]; const void* tb2 = d_in[15];

  float* out_f  = (float*)d_out;
  float* reconO = out_f;                      // 3,145,728
  float* lossO  = out_f + 3407872;            // 4
  float* qO     = out_f + 3407876;            // 16,777,216  [b][d][hw]

  char* p = (char*)d_ws;
  float* PA   = (float*)p;                     // 64MB: h1 -> h3 -> D1(lower 32MB)
  float* PB   = (float*)(p + 67108864);        // 64MB: h2(lower) -> z/res -> D2
  float* cnh  = (float*)(p + 50331648);        // 16KB  (PA dead zone, post-conv4)
  int*   idxB = (int*)  (p + 50348032);        // 1MB
  int*   flg  = (int*)  (p + 51396608);        // 256KB
  float* lossP= (float*)(p + 51658752);        // 256KB (ends < 64MB)

  k_conv1<<<65536, 256, 0, stream>>>(x, w1, b1, PA);
  k_conv2<<<dim3(32,16,2), 256, 0, stream>>>(PA, w2, b2, PB);
  k_conv3x3<128,true ,false,false><<<dim3(32,16,4), 256, 0, stream>>>(PB, w3, b3, PA);
  k_conv3x3<256,false,false,true ><<<dim3(32,16,4), 256, 0, stream>>>(PA, w4, b4, PB);
  k_cnh<<<4096, 256, 0, stream>>>(cb, cnh);

  for (int q=0; q<4; q++){
    long long koff = (long long)q * 262144;
    k_argmin<<<1024, 256, 0, stream>>>(PB, cb, koff, cnh + q*1024, idxB + q*65536, flg);
    k_fixup <<<1024, 256, 0, stream>>>(PB, cb, koff, flg, idxB + q*65536);
    if (q == 0) k_update<true ><<<65536, 256, 0, stream>>>(cb, koff, idxB,            PB, qO, lossP);
    else        k_update<false><<<65536, 256, 0, stream>>>(cb, koff, idxB + q*65536, PB, qO, lossP);
    k_lossred<<<1, 256, 0, stream>>>(lossP, lossO + q);
  }

  k_write_idx<<<1024, 256, 0, stream>>>(idxB, out_f);

  k_conv3x3<256,true,true,false><<<dim3(32,16,2), 256, 0, stream>>>(qO, dw1, db1, PA);
  k_deconv1<<<dim3(128,16,1), 256, 0, stream>>>(PA, tw1, tb1, PB);
  k_deconv2<<<12288, 256, 0, stream>>>(PB, tw2, tb2, reconO);
}

// Round 5
// 8501.000 us; speedup vs baseline: 1.3194x; 1.3194x over previous
//
#include <hip/hip_runtime.h>
#include <hip/hip_bf16.h>
#include <math.h>

// ---------------------------------------------------------------------------
// SecretRQVAE. d_out FLOAT32. Inputs runtime-sniffed (bf16 vs f32).
// Outputs (f32): recon[3145728] | indices[262144] | loss[4] | q_chw[16777216]
// Workspace (128 MB): PA [0,64MB): h1 -> h3 -> D1(lower 32MB); small bufs at
// +48MB (live only post-conv4). PB [64,128MB): h2 -> z/res [d][n] -> D2.
//
// R4 counters: conv3x3 class = 9ms of 11.2ms, 17TF, VALU 37%, LDS-bound with
// 1.2e8 bank conflicts; fixup pathological (tau 100x too loose + rolled f64
// loop). R5: conv3x3 retiled 8px x 8co/thread with float4 LDS reads keeping
// the EXACT per-output FMA order (bias -> cc asc -> dy asc -> dx asc) so z is
// bit-identical; fixup tau tightened to ~2e-3 (f32 err <= ~3e-4) + unrolled.
// ---------------------------------------------------------------------------

#define DEVFN static __device__ __forceinline__
DEVFN float b2f(__hip_bfloat16 v){ return __bfloat162float(v); }
DEVFN float ldv(const float* p, long long i){ return p[i]; }
DEVFN float ldv(const __hip_bfloat16* p, long long i){ return b2f(p[i]); }

DEVFN bool sniff_f32(const void* p){
  const unsigned* u = (const unsigned*)p;
  int hits = 0;
  #pragma unroll
  for (int i=0;i<64;i++){
    unsigned b = (u[i]>>7)&0xFFu;
    hits += (b>=118u && b<=134u) ? 1 : 0;
  }
  return hits < 32;
}

// ============================ conv1: 3->64, 4x4 s2 p1, relu ==================
template<class T>
DEVFN void conv1_impl(const T* __restrict__ x, const T* __restrict__ w,
                      const T* __restrict__ bias, float* __restrict__ out,
                      float* ws, float* bs)
{
  for (int i = threadIdx.x; i < 3072; i += 256) ws[i] = ldv(w, i);
  if (threadIdx.x < 64) bs[threadIdx.x] = ldv(bias, threadIdx.x);
  __syncthreads();
  int gid = blockIdx.x*256 + threadIdx.x;            // ((b*64+co)*128+oy)*128+ox
  int ox = gid & 127, oy = (gid>>7)&127, co = (gid>>14)&63, b = gid>>20;
  float acc = bs[co];
  const T* xb = x + (long long)b*196608;
  for (int ci=0; ci<3; ci++){
    #pragma unroll
    for (int ky=0; ky<4; ky++){
      int iy = 2*oy + ky - 1;
      if ((unsigned)iy >= 256u) continue;
      #pragma unroll
      for (int kx=0; kx<4; kx++){
        int ix = 2*ox + kx - 1;
        if ((unsigned)ix >= 256u) continue;
        acc += ldv(xb, (ci*256+iy)*256+ix) * ws[(co*3+ci)*16 + ky*4+kx];
      }
    }
  }
  out[gid] = fmaxf(acc, 0.f);
}

__global__ __launch_bounds__(256) void k_conv1(const void* x, const void* w,
    const void* bias, float* out)
{
  __shared__ float ws[3072]; __shared__ float bs[64];
  if (sniff_f32(w)) conv1_impl((const float*)x, (const float*)w, (const float*)bias, out, ws, bs);
  else conv1_impl((const __hip_bfloat16*)x, (const __hip_bfloat16*)w, (const __hip_bfloat16*)bias, out, ws, bs);
}

// ============================ conv2: 64->128, 4x4 s2 p1, relu ================
template<class TW>
DEVFN void conv2_impl(const float* __restrict__ in, const TW* __restrict__ w,
                      const TW* __restrict__ bias, float* __restrict__ out,
                      float* lin, float* lw, float* lb)
{
  const int tid = threadIdx.x;
  const int tx = blockIdx.x & 3, ty = blockIdx.x >> 2;  // 4 x-tiles, 8 y-tiles
  const int b = blockIdx.y, cg = blockIdx.z;
  if (tid < 64) lb[tid] = ldv(bias, cg*64+tid);
  __syncthreads();
  const int pxg = tid & 31, cog = tid >> 5;
  const int y = pxg >> 2, xb = (pxg & 3) << 2;
  float acc[4][8];
  #pragma unroll
  for (int i=0;i<4;i++)
    #pragma unroll
    for (int j=0;j<8;j++) acc[i][j] = lb[cog*8+j];
  const int oy0 = ty*8, ox0 = tx*16;
  const int iy0 = 2*oy0 - 1, ix0 = 2*ox0 - 1;
  for (int cc0 = 0; cc0 < 64; cc0 += 4){
    for (int j = tid; j < 4*18*34; j += 256){
      int cc = j / 612, rem = j % 612, r = rem / 34, cx = rem % 34;
      int iy = iy0 + r, ix = ix0 + cx;
      float v = 0.f;
      if ((unsigned)iy < 128u && (unsigned)ix < 128u)
        v = in[((b*64 + cc0+cc)*128 + iy)*128 + ix];
      lin[(cc*18 + r)*35 + cx] = v;
    }
    for (int j = tid; j < 4096; j += 256){
      int tap = j & 15, cc = (j>>4) & 3, co = j >> 6;
      lw[(cc*16+tap)*68 + co] = ldv(w, ((cg*64+co)*64 + cc0+cc)*16 + tap);
    }
    __syncthreads();
    #pragma unroll
    for (int cc=0; cc<4; cc++){
      #pragma unroll
      for (int ky=0; ky<4; ky++){
        #pragma unroll
        for (int kx=0; kx<4; kx++){
          float a0 = lin[(cc*18 + 2*y+ky)*35 + 2*(xb+0)+kx];
          float a1 = lin[(cc*18 + 2*y+ky)*35 + 2*(xb+1)+kx];
          float a2 = lin[(cc*18 + 2*y+ky)*35 + 2*(xb+2)+kx];
          float a3 = lin[(cc*18 + 2*y+ky)*35 + 2*(xb+3)+kx];
          const float* wp = &lw[(cc*16 + ky*4+kx)*68 + cog*8];
          #pragma unroll
          for (int j=0;j<8;j++){
            float wv = wp[j];
            acc[0][j] += a0*wv; acc[1][j] += a1*wv;
            acc[2][j] += a2*wv; acc[3][j] += a3*wv;
          }
        }
      }
    }
    __syncthreads();
  }
  #pragma unroll
  for (int j=0;j<8;j++){
    int co = cg*64 + cog*8 + j;
    #pragma unroll
    for (int i=0;i<4;i++)
      out[((b*128 + co)*64 + oy0+y)*64 + ox0+xb+i] = fmaxf(acc[i][j], 0.f);
  }
}

__global__ __launch_bounds__(256) void k_conv2(const float* in, const void* w,
    const void* bias, float* out)
{
  __shared__ __align__(16) float lin[4*18*35];
  __shared__ __align__(16) float lw[4*16*68];
  __shared__ float lb[64];
  if (sniff_f32(w)) conv2_impl(in, (const float*)w, (const float*)bias, out, lin, lw, lb);
  else conv2_impl(in, (const __hip_bfloat16*)w, (const __hip_bfloat16*)bias, out, lin, lw, lb);
}

// ============================ 3x3 s1 p1 conv (conv3/conv4/dec1) =============
// Tile 32w x 8h, 64 co/block; thread = 8px x 8co. Per-output FMA sequence is
// bias -> cc asc -> dy asc -> dx asc == round-4 kernel -> z bit-identical.
// IN_Q: input is q_chw in d_out, layout [b][c][hw]. OUT_T: write z as [d][n].
template<int CI, bool RELU, bool IN_Q, bool OUT_T, class TW>
DEVFN void conv3_impl(const float* __restrict__ in, const TW* __restrict__ w,
                      const TW* __restrict__ bias, float* __restrict__ out,
                      float* lin, float* lw, float* lb)
{
  const int tid = threadIdx.x;
  const int tx = blockIdx.x & 1, ty = blockIdx.x >> 1;   // 2 x-tiles, 8 y-tiles
  const int b = blockIdx.y, cg = blockIdx.z;
  const int CO = gridDim.z * 64;
  if (tid < 64) lb[tid] = ldv(bias, cg*64+tid);
  __syncthreads();
  const int pxg = tid & 31, cog = tid >> 5;
  const int y = pxg >> 2, xb = (pxg & 3) << 3;           // 0,8,16,24
  const int oy0 = ty*8, ox0 = tx*32;
  float acc[8][8];
  #pragma unroll
  for (int i=0;i<8;i++)
    #pragma unroll
    for (int j=0;j<8;j++) acc[i][j] = lb[cog*8+j];
  for (int cc0 = 0; cc0 < CI; cc0 += 8){
    // stage input slab: 8cc x 10 rows x 34 cols (row stride 40, 16B aligned)
    for (int j = tid; j < 2720; j += 256){
      int cc = j / 340, rem = j % 340, r = rem / 34, cx = rem % 34;
      int iy = oy0 - 1 + r, ix = ox0 - 1 + cx;
      float v = 0.f;
      if ((unsigned)iy < 64u && (unsigned)ix < 64u)
        v = IN_Q ? in[b*1048576 + (cc0+cc)*4096 + iy*64 + ix]
                 : in[((b*CI + cc0+cc)*64 + iy)*64 + ix];
      lin[(cc*10 + r)*40 + cx] = v;
    }
    // stage weights: 8cc x 9tap x 64co (co stride 68, 16B aligned)
    for (int j = tid; j < 4608; j += 256){
      int tap = j % 9, cc = (j/9) & 7, co = j / 72;
      lw[(cc*9+tap)*68 + co] = ldv(w, ((cg*64+co)*CI + cc0+cc)*9 + tap);
    }
    __syncthreads();
    #pragma unroll
    for (int cc=0; cc<8; cc++){
      #pragma unroll
      for (int dy=0; dy<3; dy++){
        const float* rowp = &lin[(cc*10 + y+dy)*40 + xb];
        float a[10];
        *(float4*)&a[0] = *(const float4*)&rowp[0];
        *(float4*)&a[4] = *(const float4*)&rowp[4];
        a[8] = rowp[8]; a[9] = rowp[9];
        #pragma unroll
        for (int dx=0; dx<3; dx++){
          const float* wp = &lw[(cc*9 + dy*3+dx)*68 + cog*8];
          float wv[8];
          *(float4*)&wv[0] = *(const float4*)&wp[0];
          *(float4*)&wv[4] = *(const float4*)&wp[4];
          #pragma unroll
          for (int j=0;j<8;j++)
            #pragma unroll
            for (int i=0;i<8;i++)
              acc[i][j] += a[i+dx]*wv[j];
        }
      }
    }
    __syncthreads();
  }
  const int oy = oy0 + y;
  #pragma unroll
  for (int j=0;j<8;j++){
    int co = cg*64 + cog*8 + j;
    #pragma unroll
    for (int i=0;i<8;i++){
      int ox = ox0 + xb + i;
      float v = acc[i][j];
      if (RELU) v = fmaxf(v, 0.f);
      if (OUT_T) out[co*65536 + b*4096 + oy*64 + ox] = v;
      else       out[((b*CO + co)*64 + oy)*64 + ox] = v;
    }
  }
}

template<int CI, bool RELU, bool IN_Q, bool OUT_T>
__global__ __launch_bounds__(256) void k_conv3x3(const float* in, const void* w,
    const void* bias, float* out)
{
  __shared__ __align__(16) float lin[8*10*40];
  __shared__ __align__(16) float lw[8*9*68];
  __shared__ float lb[64];
  if (sniff_f32(w)) conv3_impl<CI,RELU,IN_Q,OUT_T>(in, (const float*)w, (const float*)bias, out, lin, lw, lb);
  else conv3_impl<CI,RELU,IN_Q,OUT_T>(in, (const __hip_bfloat16*)w, (const __hip_bfloat16*)bias, out, lin, lw, lb);
}

// ============================ codebook 0.5*||c||^2 ===========================
template<class T>
DEVFN void cnh_impl(const T* __restrict__ cb, float* __restrict__ cnh, float* ps)
{
  int row = blockIdx.x;                  // q*1024 + k
  float v = ldv(cb, (long long)row*256 + threadIdx.x);
  float s = v*v;
  for (int o=32;o>0;o>>=1) s += __shfl_down(s, o, 64);
  if ((threadIdx.x & 63) == 0) ps[threadIdx.x>>6] = s;
  __syncthreads();
  if (threadIdx.x == 0) cnh[row] = 0.5f*(ps[0]+ps[1]+ps[2]+ps[3]);
}

__global__ __launch_bounds__(256) void k_cnh(const void* cb, float* cnh)
{
  __shared__ float ps[4];
  if (sniff_f32(cb)) cnh_impl((const float*)cb, cnh, ps);
  else cnh_impl((const __hip_bfloat16*)cb, cnh, ps);
}

// ============================ VQ argmin (f32) with near-tie flag =============
template<class TCB>
DEVFN void argmin_impl(const float* __restrict__ resT, const TCB* __restrict__ cb,
    long long koff, const float* __restrict__ cnh,
    int* __restrict__ idxOut, int* __restrict__ flagOut,
    float* lp, float* lc, float* rm1, float* rm2, int* ri1)
{
  const int tid = threadIdx.x;
  const int n0 = blockIdx.x * 64;
  const int tp = tid & 15, tc = tid >> 4;
  float m1[4], m2[4]; int i1[4];
  #pragma unroll
  for (int i=0;i<4;i++){ m1[i]=INFINITY; m2[i]=INFINITY; i1[i]=0; }
  for (int ct=0; ct<8; ct++){
    const int k0 = ct*128;
    float acc[4][8];
    #pragma unroll
    for (int i=0;i<4;i++)
      #pragma unroll
      for (int j=0;j<8;j++) acc[i][j]=0.f;
    for (int dc=0; dc<8; dc++){
      const int d0 = dc*32;
      for (int j=tid; j<2048; j+=256){ int dd=j>>6, p=j&63; lp[dd*64+p] = resT[(d0+dd)*65536 + n0+p]; }
      for (int j=tid; j<4096; j+=256){ int dd=j&31, kk=j>>5; lc[dd*132+kk] = ldv(cb, koff + (long long)(k0+kk)*256 + d0+dd); }
      __syncthreads();
      #pragma unroll 4
      for (int dd=0; dd<32; dd++){
        float a[4]; float c[8];
        *(float4*)&a[0] = *(const float4*)&lp[dd*64 + 4*tp];
        *(float4*)&c[0] = *(const float4*)&lc[dd*132 + 8*tc];
        *(float4*)&c[4] = *(const float4*)&lc[dd*132 + 8*tc + 4];
        #pragma unroll
        for (int i=0;i<4;i++)
          #pragma unroll
          for (int j=0;j<8;j++) acc[i][j] += a[i]*c[j];
      }
      __syncthreads();
    }
    #pragma unroll
    for (int j=0;j<8;j++){
      int k = k0 + 8*tc + j;
      float cn = cnh[k];
      #pragma unroll
      for (int i=0;i<4;i++){
        float s = cn - acc[i][j];
        if (s < m1[i]) { m2[i] = m1[i]; m1[i] = s; i1[i] = k; }
        else if (s < m2[i]) m2[i] = s;
      }
    }
  }
  #pragma unroll
  for (int i=0;i<4;i++){
    rm1[(4*tp+i)*17 + tc] = m1[i];
    rm2[(4*tp+i)*17 + tc] = m2[i];
    ri1[(4*tp+i)*17 + tc] = i1[i];
  }
  __syncthreads();
  if (tid < 64){
    float bm1 = INFINITY, bm2 = INFINITY; int bi = 0;
    for (int t=0;t<16;t++){
      float a = rm1[tid*17+t], b2v = rm2[tid*17+t]; int ia = ri1[tid*17+t];
      if (a < bm1 || (a == bm1 && ia < bi)){ bm2 = fminf(bm1, b2v); bm1 = a; bi = ia; }
      else bm2 = fminf(bm2, fminf(a, b2v));
    }
    idxOut[n0 + tid] = bi;
    // f32 worst-case dot error ~3e-4; tau ~2e-3 keeps a 6x margin while cutting
    // the flag rate ~50x vs round-4's 1e-3*(|bm1|+1).
    float tau = 1e-3f + 1e-5f*fabsf(bm1);
    flagOut[n0 + tid] = (bm2 - bm1 < tau) ? 1 : 0;
  }
}

__global__ __launch_bounds__(256) void k_argmin(const float* resT, const void* cb,
    long long koff, const float* cnh, int* idxOut, int* flagOut)
{
  __shared__ __align__(16) float lp[32*64];
  __shared__ __align__(16) float lc[32*132];
  __shared__ float rm1[64*17], rm2[64*17];
  __shared__ int   ri1[64*17];
  if (sniff_f32(cb)) argmin_impl(resT, (const float*)cb, koff, cnh, idxOut, flagOut, lp, lc, rm1, rm2, ri1);
  else argmin_impl(resT, (const __hip_bfloat16*)cb, koff, cnh, idxOut, flagOut, lp, lc, rm1, rm2, ri1);
}

// ============================ f64 fixup for near-tie points ==================
template<class TCB>
DEVFN void fixup_impl(const float* __restrict__ resT, const TCB* __restrict__ cb,
    long long koff, const int* __restrict__ flags, int* __restrict__ idxOut,
    double* bm, int* bis, float* rsh)
{
  const int tid = threadIdx.x;
  const int n0 = blockIdx.x * 64;
  for (int p=0; p<64; p++){
    int n = n0 + p;
    if (!flags[n]) continue;                 // uniform per block
    rsh[tid] = resT[tid*65536 + n];
    __syncthreads();
    double best = INFINITY; int bidx = 0;
    for (int c=0; c<4; c++){
      int k = tid*4 + c;
      long long base = koff + (long long)k*256;
      double s0=0.0, s1=0.0, s2=0.0, s3=0.0;
      #pragma unroll 8
      for (int d=0; d<256; d+=4){
        double c0 = (double)ldv(cb, base+d);
        double c1 = (double)ldv(cb, base+d+1);
        double c2 = (double)ldv(cb, base+d+2);
        double c3 = (double)ldv(cb, base+d+3);
        s0 += c0*(c0 - 2.0*(double)rsh[d]);
        s1 += c1*(c1 - 2.0*(double)rsh[d+1]);
        s2 += c2*(c2 - 2.0*(double)rsh[d+2]);
        s3 += c3*(c3 - 2.0*(double)rsh[d+3]);
      }
      double s = (s0+s1)+(s2+s3);
      if (s < best || (s == best && k < bidx)){ best = s; bidx = k; }
    }
    bm[tid] = best; bis[tid] = bidx;
    __syncthreads();
    for (int st=128; st>0; st>>=1){
      if (tid < st){
        if (bm[tid+st] < bm[tid] || (bm[tid+st] == bm[tid] && bis[tid+st] < bis[tid])){
          bm[tid] = bm[tid+st]; bis[tid] = bis[tid+st];
        }
      }
      __syncthreads();
    }
    if (tid == 0) idxOut[n] = bis[0];
    __syncthreads();
  }
}

__global__ __launch_bounds__(256) void k_fixup(const float* resT, const void* cb,
    long long koff, const int* flags, int* idxOut)
{
  __shared__ double bm[256]; __shared__ int bis[256];
  __shared__ float rsh[256];
  if (sniff_f32(cb)) fixup_impl(resT, (const float*)cb, koff, flags, idxOut, bm, bis, rsh);
  else fixup_impl(resT, (const __hip_bfloat16*)cb, koff, flags, idxOut, bm, bis, rsh);
}

// ============================ VQ update: gather, loss, residual, q-accum =====
template<bool FIRST, class TCB>
DEVFN void update_impl(const TCB* __restrict__ cb, long long koff,
    const int* __restrict__ idx, float* __restrict__ resT,
    float* __restrict__ qf, float* __restrict__ lossP, float* ps)
{
  int gid = blockIdx.x*256 + threadIdx.x;    // [d][n], n fastest
  int n = gid & 65535, d = gid >> 16;
  int b = n >> 12, hw = n & 4095;
  float r = resT[gid];
  float qv = ldv(cb, koff + (long long)idx[n]*256 + d);
  float diff = qv - r;
  resT[gid] = -diff;
  long long qo = (long long)b*1048576 + d*4096 + hw;   // [b][d][hw]
  qf[qo] = FIRST ? qv : (qf[qo] + qv);
  float t = diff*diff;
  for (int o=32;o>0;o>>=1) t += __shfl_down(t, o, 64);
  if ((threadIdx.x & 63) == 0) ps[threadIdx.x>>6] = t;
  __syncthreads();
  if (threadIdx.x == 0) lossP[blockIdx.x] = ps[0]+ps[1]+ps[2]+ps[3];
}

template<bool FIRST>
__global__ __launch_bounds__(256) void k_update(const void* cb, long long koff,
    const int* idx, float* resT, float* qf, float* lossP)
{
  __shared__ float ps[4];
  if (sniff_f32(cb)) update_impl<FIRST>((const float*)cb, koff, idx, resT, qf, lossP, ps);
  else update_impl<FIRST>((const __hip_bfloat16*)cb, koff, idx, resT, qf, lossP, ps);
}

__global__ __launch_bounds__(256) void k_lossred(const float* __restrict__ lossP,
    float* __restrict__ outp)
{
  double s = 0.0;
  for (int j = threadIdx.x; j < 65536; j += 256) s += (double)lossP[j];
  for (int o=32;o>0;o>>=1) s += __shfl_down(s, o, 64);
  __shared__ double ps[4];
  if ((threadIdx.x & 63) == 0) ps[threadIdx.x>>6] = s;
  __syncthreads();
  if (threadIdx.x == 0) *outp = (float)((ps[0]+ps[1]+ps[2]+ps[3]) / 16777216.0);
}

// ============================ indices writer =================================
__global__ __launch_bounds__(256) void k_write_idx(const int* __restrict__ idxAll,
    float* __restrict__ out)
{
  int gid = blockIdx.x*256 + threadIdx.x;    // ((b*4+q)*4096 + hw)
  int hw = gid & 4095, q = (gid>>12)&3, b = gid>>14;
  out[3145728 + gid] = (float)idxAll[q*65536 + b*4096 + hw];
}

// ============================ deconv1: 128->64, 4x4 s2 p1, relu ==============
template<class TW>
DEVFN void deconv1_impl(const float* __restrict__ in, const TW* __restrict__ w,
                        const TW* __restrict__ bias, float* __restrict__ out,
                        float* lin, float* lw, float* lb)
{
  const int tid = threadIdx.x;
  const int tx = blockIdx.x & 7, ty = blockIdx.x >> 3;   // 8 x-tiles, 16 y-tiles
  const int b = blockIdx.y;
  if (tid < 64) lb[tid] = ldv(bias, tid);
  __syncthreads();
  const int pxg = tid & 31, cog = tid >> 5;
  const int y = pxg >> 2, xb = (pxg & 3) << 2;
  float acc[4][8];
  #pragma unroll
  for (int i=0;i<4;i++)
    #pragma unroll
    for (int j=0;j<8;j++) acc[i][j] = lb[cog*8+j];
  const int oy0 = ty*8, ox0 = tx*16;
  const int iy0 = oy0 >> 1, ix0 = ox0 >> 1;
  const int kb = (y+1) & 1;
  const int e  = (y+1-kb) >> 1;
  for (int cc0 = 0; cc0 < 128; cc0 += 8){
    for (int j = tid; j < 480; j += 256){
      int cc = j / 60, r = (j % 60) / 10, cx = j % 10;
      int iy = iy0 - 1 + r, ix = ix0 - 1 + cx;
      float v = 0.f;
      if ((unsigned)iy < 64u && (unsigned)ix < 64u)
        v = in[((b*128 + cc0+cc)*64 + iy)*64 + ix];
      lin[(cc*6 + r)*11 + cx] = v;
    }
    for (int j = tid; j < 8192; j += 256){
      int tap = j & 15, co = (j>>4) & 63, cc = j >> 10;
      lw[(cc*16+tap)*68 + co] = ldv(w, ((cc0+cc)*64 + co)*16 + tap);
    }
    __syncthreads();
    #pragma unroll
    for (int cc=0; cc<8; cc++){
      #pragma unroll
      for (int kyi=0; kyi<2; kyi++){
        int ky = kb + 2*kyi;
        int riy = e - kyi + 1;
        #pragma unroll
        for (int kxi=0; kxi<2; kxi++){
          int rx = (xb>>1) - kxi;
          float a0 = lin[(cc*6 + riy)*11 + rx+1];
          float a1 = lin[(cc*6 + riy)*11 + rx+2];
          float a3 = lin[(cc*6 + riy)*11 + rx+3];
          const float* we = &lw[(cc*16 + ky*4 + 1 + 2*kxi)*68 + cog*8];
          const float* wo = &lw[(cc*16 + ky*4 + 0 + 2*kxi)*68 + cog*8];
          #pragma unroll
          for (int j=0;j<8;j++){
            acc[0][j] += a0*we[j];
            acc[1][j] += a1*wo[j];
            acc[2][j] += a1*we[j];
            acc[3][j] += a3*wo[j];
          }
        }
      }
    }
    __syncthreads();
  }
  #pragma unroll
  for (int j=0;j<8;j++){
    int co = cog*8 + j;
    #pragma unroll
    for (int i=0;i<4;i++)
      out[((b*64 + co)*128 + oy0+y)*128 + ox0+xb+i] = fmaxf(acc[i][j], 0.f);
  }
}

__global__ __launch_bounds__(256) void k_deconv1(const float* in, const void* w,
    const void* bias, float* out)
{
  __shared__ __align__(16) float lin[8*6*11];
  __shared__ __align__(16) float lw[8*16*68];
  __shared__ float lb[64];
  if (sniff_f32(w)) deconv1_impl(in, (const float*)w, (const float*)bias, out, lin, lw, lb);
  else deconv1_impl(in, (const __hip_bfloat16*)w, (const __hip_bfloat16*)bias, out, lin, lw, lb);
}

// ============================ deconv2: 64->3, 4x4 s2 p1, tanh ================
template<class TW>
DEVFN void deconv2_impl(const float* __restrict__ in, const TW* __restrict__ w,
                        const TW* __restrict__ bias, float* __restrict__ outp,
                        float* lw, float* lb)
{
  for (int j = threadIdx.x; j < 3072; j += 256) lw[j] = ldv(w, j);
  if (threadIdx.x < 3) lb[threadIdx.x] = ldv(bias, threadIdx.x);
  __syncthreads();
  int gid = blockIdx.x*256 + threadIdx.x;    // ((b*3+co)*256+oy)*256+ox
  int ox = gid & 255, oy = (gid>>8)&255;
  int c3 = gid >> 16; int co = c3 % 3; int b = c3 / 3;
  int kby = (oy+1)&1, kbx = (ox+1)&1;
  float acc = lb[co];
  const float* inb = in + (long long)b*64*16384;
  for (int ci=0; ci<64; ci++){
    const float* ic = inb + ci*16384;
    #pragma unroll
    for (int kyi=0; kyi<2; kyi++){
      int ky = kby + 2*kyi;
      int iy = oy + 1 - ky;
      if (iy < 0) continue;
      iy >>= 1;
      if (iy >= 128) continue;
      #pragma unroll
      for (int kxi=0; kxi<2; kxi++){
        int kx = kbx + 2*kxi;
        int ix = ox + 1 - kx;
        if (ix < 0) continue;
        ix >>= 1;
        if (ix >= 128) continue;
        acc += ic[iy*128+ix] * lw[(ci*3+co)*16 + ky*4+kx];
      }
    }
  }
  outp[gid] = tanhf(acc);
}

__global__ __launch_bounds__(256) void k_deconv2(const float* in, const void* w,
    const void* bias, float* outp)
{
  __shared__ float lw[3072]; __shared__ float lb[3];
  if (sniff_f32(w)) deconv2_impl(in, (const float*)w, (const float*)bias, outp, lw, lb);
  else deconv2_impl(in, (const __hip_bfloat16*)w, (const __hip_bfloat16*)bias, outp, lw, lb);
}

// ============================ launch =========================================
extern "C" void kernel_launch(void* const* d_in, const int* in_sizes, int n_in,
                              void* d_out, int out_size, void* d_ws, size_t ws_size,
                              hipStream_t stream)
{
  const void* x   = d_in[0];
  const void* w1  = d_in[1];  const void* b1  = d_in[2];
  const void* w2  = d_in[3];  const void* b2  = d_in[4];
  const void* w3  = d_in[5];  const void* b3  = d_in[6];
  const void* w4  = d_in[7];  const void* b4  = d_in[8];
  const void* cb  = d_in[9];
  const void* dw1 = d_in[10]; const void* db1 = d_in[11];
  const void* tw1 = d_in[12]; const void* tb1 = d_in[13];
  const void* tw2 = d_in[14]; const void* tb2 = d_in[15];

  float* out_f  = (float*)d_out;
  float* reconO = out_f;                      // 3,145,728
  float* lossO  = out_f + 3407872;            // 4
  float* qO     = out_f + 3407876;            // 16,777,216  [b][d][hw]

  char* p = (char*)d_ws;
  float* PA   = (float*)p;                     // 64MB: h1 -> h3 -> D1(lower 32MB)
  float* PB   = (float*)(p + 67108864);        // 64MB: h2(lower) -> z/res -> D2
  float* cnh  = (float*)(p + 50331648);        // 16KB  (PA dead zone, post-conv4)
  int*   idxB = (int*)  (p + 50348032);        // 1MB
  int*   flg  = (int*)  (p + 51396608);        // 256KB
  float* lossP= (float*)(p + 51658752);        // 256KB (ends < 64MB)

  k_conv1<<<65536, 256, 0, stream>>>(x, w1, b1, PA);
  k_conv2<<<dim3(32,16,2), 256, 0, stream>>>(PA, w2, b2, PB);
  k_conv3x3<128,true ,false,false><<<dim3(16,16,4), 256, 0, stream>>>(PB, w3, b3, PA);
  k_conv3x3<256,false,false,true ><<<dim3(16,16,4), 256, 0, stream>>>(PA, w4, b4, PB);
  k_cnh<<<4096, 256, 0, stream>>>(cb, cnh);

  for (int q=0; q<4; q++){
    long long koff = (long long)q * 262144;
    k_argmin<<<1024, 256, 0, stream>>>(PB, cb, koff, cnh + q*1024, idxB + q*65536, flg);
    k_fixup <<<1024, 256, 0, stream>>>(PB, cb, koff, flg, idxB + q*65536);
    if (q == 0) k_update<true ><<<65536, 256, 0, stream>>>(cb, koff, idxB,            PB, qO, lossP);
    else        k_update<false><<<65536, 256, 0, stream>>>(cb, koff, idxB + q*65536, PB, qO, lossP);
    k_lossred<<<1, 256, 0, stream>>>(lossP, lossO + q);
  }

  k_write_idx<<<1024, 256, 0, stream>>>(idxB, out_f);

  k_conv3x3<256,true,true,false><<<dim3(16,16,2), 256, 0, stream>>>(qO, dw1, db1, PA);
  k_deconv1<<<dim3(128,16,1), 256, 0, stream>>>(PA, tw1, tb1, PB);
  k_deconv2<<<12288, 256, 0, stream>>>(PB, tw2, tb2, reconO);
}